// Round 4
// baseline (727.092 us; speedup 1.0000x reference)
//
#include <hip/hip_runtime.h>
#include <stdint.h>

typedef unsigned short u16;
typedef __bf16 bf16x8 __attribute__((ext_vector_type(8)));
typedef float f32x4 __attribute__((ext_vector_type(4)));

__device__ __forceinline__ f32x4 mfma16(bf16x8 a, bf16x8 b, f32x4 c) {
    return __builtin_amdgcn_mfma_f32_16x16x32_bf16(a, b, c, 0, 0, 0);
}

__device__ __forceinline__ u16 f2b(float f) {
    union { float f; unsigned u32; } v; v.f = f;
    unsigned b = v.u32;
    unsigned r = b + 0x7FFFu + ((b >> 16) & 1u);   // round-to-nearest-even
    return (u16)(r >> 16);
}

// load 8 consecutive fp32 and convert to a bf16x8 fragment
__device__ __forceinline__ bf16x8 cvt8(const float* __restrict__ p) {
    float4 v0 = *(const float4*)p;
    float4 v1 = *(const float4*)(p + 4);
    bf16x8 r;
    r[0] = (__bf16)v0.x; r[1] = (__bf16)v0.y; r[2] = (__bf16)v0.z; r[3] = (__bf16)v0.w;
    r[4] = (__bf16)v1.x; r[5] = (__bf16)v1.y; r[6] = (__bf16)v1.z; r[7] = (__bf16)v1.w;
    return r;
}

// ---------------------------------------------------------------------------
// QKV projection: A[M,K] fp32, W[N,K] fp32, bias fp32 -> bf16 out.
// C = A @ W^T + bias. grid.y selects (W,bias,out).
// Wave computes a 32x32 tile via 2x2 of 16x16x32 MFMAs; fp32->bf16 in regs.
// A-frag: lane holds A[m0 + (l&15)][k0 + (l>>4)*8 + j]
// B-frag: lane holds W[n0 + (l&15)][k0 + (l>>4)*8 + j]
// D:      C[m0 + (l>>4)*4 + r][n0 + (l&15)]
// ---------------------------------------------------------------------------
__global__ __launch_bounds__(256) void gemm_qkv(
    const float* __restrict__ A,
    const float* __restrict__ W0, const float* __restrict__ W1, const float* __restrict__ W2,
    const float* __restrict__ B0, const float* __restrict__ B1, const float* __restrict__ B2,
    u16* __restrict__ O0, u16* __restrict__ O1, u16* __restrict__ O2,
    int M, int N, int K)
{
    const int sel = blockIdx.y;
    const float* W    = sel == 0 ? W0 : (sel == 1 ? W1 : W2);
    const float* bias = sel == 0 ? B0 : (sel == 1 ? B1 : B2);
    u16* O            = sel == 0 ? O0 : (sel == 1 ? O1 : O2);

    const int lane = threadIdx.x & 63;
    const int wid  = threadIdx.x >> 6;
    const int l15  = lane & 15;
    const int quad = lane >> 4;

    const int ntiles2 = N >> 5;
    const int waveId  = blockIdx.x * 4 + wid;
    const int mt = waveId / ntiles2;
    const int nt = waveId % ntiles2;
    const int m0 = mt << 5, n0 = nt << 5;

    f32x4 acc00 = {0.f, 0.f, 0.f, 0.f};
    f32x4 acc01 = acc00, acc10 = acc00, acc11 = acc00;

    const float* a0p = A + (size_t)(m0 + l15) * K + quad * 8;
    const float* a1p = a0p + (size_t)16 * K;
    const float* b0p = W + (size_t)(n0 + l15) * K + quad * 8;
    const float* b1p = b0p + (size_t)16 * K;

    for (int k0 = 0; k0 < K; k0 += 32) {
        bf16x8 a0 = cvt8(a0p + k0);
        bf16x8 a1 = cvt8(a1p + k0);
        bf16x8 b0 = cvt8(b0p + k0);
        bf16x8 b1 = cvt8(b1p + k0);
        acc00 = mfma16(a0, b0, acc00);
        acc01 = mfma16(a0, b1, acc01);
        acc10 = mfma16(a1, b0, acc10);
        acc11 = mfma16(a1, b1, acc11);
    }

    const float bias0 = bias[n0 + l15];
    const float bias1 = bias[n0 + 16 + l15];
#pragma unroll
    for (int r = 0; r < 4; ++r) {
        const size_t row0 = (size_t)(m0 + quad * 4 + r) * N;
        const size_t row1 = row0 + (size_t)16 * N;
        O[row0 + n0 + l15]      = f2b(acc00[r] + bias0);
        O[row0 + n0 + 16 + l15] = f2b(acc01[r] + bias1);
        O[row1 + n0 + l15]      = f2b(acc10[r] + bias0);
        O[row1 + n0 + 16 + l15] = f2b(acc11[r] + bias1);
    }
}

// ---------------------------------------------------------------------------
// Output projection: A[M,K] bf16 (ctx), W[N,K] fp32, bias fp32 -> FP32 out
// (reference output dtype is float32).
// ---------------------------------------------------------------------------
__global__ __launch_bounds__(256) void gemm_out(
    const u16* __restrict__ A, const float* __restrict__ W,
    const float* __restrict__ bias, float* __restrict__ O,
    int M, int N, int K)
{
    const int lane = threadIdx.x & 63;
    const int wid  = threadIdx.x >> 6;
    const int l15  = lane & 15;
    const int quad = lane >> 4;

    const int ntiles2 = N >> 5;
    const int waveId  = blockIdx.x * 4 + wid;
    const int mt = waveId / ntiles2;
    const int nt = waveId % ntiles2;
    const int m0 = mt << 5, n0 = nt << 5;

    f32x4 acc00 = {0.f, 0.f, 0.f, 0.f};
    f32x4 acc01 = acc00, acc10 = acc00, acc11 = acc00;

    const u16* a0p = A + (size_t)(m0 + l15) * K + quad * 8;
    const u16* a1p = a0p + (size_t)16 * K;
    const float* b0p = W + (size_t)(n0 + l15) * K + quad * 8;
    const float* b1p = b0p + (size_t)16 * K;

    for (int k0 = 0; k0 < K; k0 += 32) {
        bf16x8 a0 = *(const bf16x8*)(a0p + k0);
        bf16x8 a1 = *(const bf16x8*)(a1p + k0);
        bf16x8 b0 = cvt8(b0p + k0);
        bf16x8 b1 = cvt8(b1p + k0);
        acc00 = mfma16(a0, b0, acc00);
        acc01 = mfma16(a0, b1, acc01);
        acc10 = mfma16(a1, b0, acc10);
        acc11 = mfma16(a1, b1, acc11);
    }

    const float bias0 = bias[n0 + l15];
    const float bias1 = bias[n0 + 16 + l15];
#pragma unroll
    for (int r = 0; r < 4; ++r) {
        const size_t row0 = (size_t)(m0 + quad * 4 + r) * N;
        const size_t row1 = row0 + (size_t)16 * N;
        O[row0 + n0 + l15]      = acc00[r] + bias0;
        O[row0 + n0 + 16 + l15] = acc01[r] + bias1;
        O[row1 + n0 + l15]      = acc10[r] + bias0;
        O[row1 + n0 + 16 + l15] = acc11[r] + bias1;
    }
}

// ---------------------------------------------------------------------------
// Flash attention, causal. Q/K/V/ctx stored as (B*S, 1024) bf16; head h uses
// columns [64h, 64h+64). One block = 4 waves = one 64-row q-tile of one (b,h).
// ctx aliases Q (each block reads only its own slice of Q before writing it).
// ---------------------------------------------------------------------------
__global__ __launch_bounds__(256) void attn_kernel(
    const u16* __restrict__ Q, const u16* __restrict__ K,
    const u16* __restrict__ V, u16* __restrict__ ctx)
{
    __shared__ __attribute__((aligned(16))) u16 Vt[64][72];  // V^T: [hd][key], +8 pad
    __shared__ __attribute__((aligned(16))) u16 Pl[64][72];  // P tile, row-major

    const int qt = blockIdx.x;
    const int h  = blockIdx.y;
    const int b  = blockIdx.z;
    const int lane = threadIdx.x & 63;
    const int wid  = threadIdx.x >> 6;
    const int l15  = lane & 15;
    const int quad = lane >> 4;
    const int q0 = qt * 64;
    const size_t rowbase = (size_t)b * 2048;
    const int cbase = h * 64;

    const u16* qrow = Q + (rowbase + q0 + wid * 16 + l15) * 1024 + cbase + quad * 8;
    const bf16x8 qa0 = *(const bf16x8*)qrow;
    const bf16x8 qa1 = *(const bf16x8*)(qrow + 32);

    f32x4 o[4];
#pragma unroll
    for (int i = 0; i < 4; ++i) o[i] = f32x4{0.f, 0.f, 0.f, 0.f};
    float m_r[4], l_r[4];
#pragma unroll
    for (int i = 0; i < 4; ++i) { m_r[i] = -1e30f; l_r[i] = 0.f; }

    for (int kt = 0; kt <= qt; ++kt) {
        const int k0 = kt * 64;
        __syncthreads();   // prior iteration's Vt/Pl reads complete

        // stage V^T into LDS (transpose during write)
        for (int idx = threadIdx.x; idx < 64 * 8; idx += 256) {
            const int r  = idx >> 3;
            const int c8 = (idx & 7) * 8;
            bf16x8 vv = *(const bf16x8*)(V + (rowbase + k0 + r) * 1024 + cbase + c8);
            const u16* vp = (const u16*)&vv;
#pragma unroll
            for (int e = 0; e < 8; ++e) Vt[c8 + e][r] = vp[e];
        }

        // S = Q K^T for this wave's strip
        f32x4 s[4];
#pragma unroll
        for (int nt = 0; nt < 4; ++nt) {
            const u16* krow = K + (rowbase + k0 + nt * 16 + l15) * 1024 + cbase + quad * 8;
            bf16x8 kb0 = *(const bf16x8*)krow;
            bf16x8 kb1 = *(const bf16x8*)(krow + 32);
            f32x4 z = {0.f, 0.f, 0.f, 0.f};
            z = mfma16(qa0, kb0, z);
            z = mfma16(qa1, kb1, z);
            s[nt] = z;
        }

        float sc[4][4];
#pragma unroll
        for (int nt = 0; nt < 4; ++nt)
#pragma unroll
            for (int r = 0; r < 4; ++r) sc[nt][r] = s[nt][r] * 0.125f;  // 1/sqrt(64)

        if (kt == qt) {  // diagonal tile: mask col > row
#pragma unroll
            for (int nt = 0; nt < 4; ++nt) {
                const int col = nt * 16 + l15;
#pragma unroll
                for (int r = 0; r < 4; ++r) {
                    const int rowIn = wid * 16 + quad * 4 + r;
                    if (col > rowIn) sc[nt][r] = -1e30f;
                }
            }
        }

        float alpha[4], p[4][4];
#pragma unroll
        for (int r = 0; r < 4; ++r) {
            float rm = fmaxf(fmaxf(sc[0][r], sc[1][r]), fmaxf(sc[2][r], sc[3][r]));
            rm = fmaxf(rm, __shfl_xor(rm, 1));
            rm = fmaxf(rm, __shfl_xor(rm, 2));
            rm = fmaxf(rm, __shfl_xor(rm, 4));
            rm = fmaxf(rm, __shfl_xor(rm, 8));
            const float mn = fmaxf(m_r[r], rm);
            alpha[r] = __expf(m_r[r] - mn);
            m_r[r] = mn;
            float rs = 0.f;
#pragma unroll
            for (int nt = 0; nt < 4; ++nt) {
                p[nt][r] = __expf(sc[nt][r] - mn);
                rs += p[nt][r];
            }
            rs += __shfl_xor(rs, 1);
            rs += __shfl_xor(rs, 2);
            rs += __shfl_xor(rs, 4);
            rs += __shfl_xor(rs, 8);
            l_r[r] = l_r[r] * alpha[r] + rs;
        }

#pragma unroll
        for (int nt = 0; nt < 4; ++nt)
#pragma unroll
            for (int r = 0; r < 4; ++r)
                Pl[wid * 16 + quad * 4 + r][nt * 16 + l15] = f2b(p[nt][r]);
#pragma unroll
        for (int nt = 0; nt < 4; ++nt)
#pragma unroll
            for (int r = 0; r < 4; ++r) o[nt][r] *= alpha[r];

        __syncthreads();   // Vt + Pl visible

        const u16* prow = &Pl[wid * 16 + l15][quad * 8];
        bf16x8 pa0 = *(const bf16x8*)prow;
        bf16x8 pa1 = *(const bf16x8*)(prow + 32);
#pragma unroll
        for (int nt = 0; nt < 4; ++nt) {
            const u16* vrow = &Vt[nt * 16 + l15][quad * 8];
            bf16x8 vb0 = *(const bf16x8*)vrow;
            bf16x8 vb1 = *(const bf16x8*)(vrow + 32);
            o[nt] = mfma16(pa0, vb0, o[nt]);
            o[nt] = mfma16(pa1, vb1, o[nt]);
        }
    }

#pragma unroll
    for (int nt = 0; nt < 4; ++nt)
#pragma unroll
        for (int r = 0; r < 4; ++r) {
            const float val = o[nt][r] / l_r[r];
            ctx[(rowbase + q0 + wid * 16 + quad * 4 + r) * 1024 + cbase + nt * 16 + l15] =
                f2b(val);
        }
}

extern "C" void kernel_launch(void* const* d_in, const int* in_sizes, int n_in,
                              void* d_out, int out_size, void* d_ws, size_t ws_size,
                              hipStream_t stream) {
    const float* x  = (const float*)d_in[0];
    const float* Wq = (const float*)d_in[1];
    const float* bq = (const float*)d_in[2];
    const float* Wk = (const float*)d_in[3];
    const float* bk = (const float*)d_in[4];
    const float* Wv = (const float*)d_in[5];
    const float* bv = (const float*)d_in[6];
    const float* Wo = (const float*)d_in[7];
    const float* bo = (const float*)d_in[8];
    float* out = (float*)d_out;              // reference output dtype = fp32

    const int N = 1024, K = 1024;
    const int M = in_sizes[0] / K;           // B*S = 4096
    const size_t MN = (size_t)M * N;

    // workspace (bf16): q (later ctx), k, v -> 24 MB. Round 2 vs 3 identity
    // proved ws >= 40 MB is valid.
    u16* q   = (u16*)d_ws;
    u16* kb  = q  + MN;
    u16* v   = kb + MN;
    u16* ctx = q;                            // alias: per-block disjoint slices

    const int gemmBlocks = (M / 32) * (N / 32) / 4;   // 1024

    gemm_qkv<<<dim3(gemmBlocks, 3, 1), 256, 0, stream>>>(
        x, Wq, Wk, Wv, bq, bk, bv, q, kb, v, M, N, K);

    attn_kernel<<<dim3(32, 16, 2), 256, 0, stream>>>(q, kb, v, ctx);

    gemm_out<<<dim3(gemmBlocks, 1, 1), 256, 0, stream>>>(
        ctx, Wo, bo, out, M, N, K);
}

// Round 5
// 320.607 us; speedup vs baseline: 2.2679x; 2.2679x over previous
//
#include <hip/hip_runtime.h>
#include <stdint.h>

typedef unsigned short u16;
typedef __bf16 bf16x8 __attribute__((ext_vector_type(8)));
typedef float f32x4 __attribute__((ext_vector_type(4)));

typedef __attribute__((address_space(3))) uint32_t lds_u32;
typedef __attribute__((address_space(1))) uint32_t glb_u32;

__device__ __forceinline__ f32x4 mfma16(bf16x8 a, bf16x8 b, f32x4 c) {
    return __builtin_amdgcn_mfma_f32_16x16x32_bf16(a, b, c, 0, 0, 0);
}

__device__ __forceinline__ u16 f2b(float f) {
    union { float f; unsigned u32; } v; v.f = f;
    unsigned b = v.u32;
    unsigned r = b + 0x7FFFu + ((b >> 16) & 1u);   // RNE
    return (u16)(r >> 16);
}

// async global->LDS, 16B per lane. LDS side must be base + lane*16 (it is:
// lane offset = (lane>>2)*64B + (lane&3)*16B = lane*16).
__device__ __forceinline__ void async16(const u16* g, u16* l) {
    __builtin_amdgcn_global_load_lds((glb_u32*)(uintptr_t)(const void*)g,
                                     (lds_u32*)l, 16, 0, 0);
}

// ---------------------------------------------------------------------------
// fp32 -> bf16 casts
// ---------------------------------------------------------------------------
__global__ __launch_bounds__(256) void cast1(const float* __restrict__ in,
                                             u16* __restrict__ out, int n) {
    const int i = (blockIdx.x * 256 + threadIdx.x) * 4;
    if (i < n) {
        float4 v = *(const float4*)(in + i);
        ushort4 o = { f2b(v.x), f2b(v.y), f2b(v.z), f2b(v.w) };
        *(ushort4*)(out + i) = o;
    }
}

__global__ __launch_bounds__(256) void cast4(
    const float* __restrict__ i0, const float* __restrict__ i1,
    const float* __restrict__ i2, const float* __restrict__ i3,
    u16* __restrict__ o0, u16* __restrict__ o1,
    u16* __restrict__ o2, u16* __restrict__ o3, int n) {
    const int s = blockIdx.y;
    const float* in = s == 0 ? i0 : (s == 1 ? i1 : (s == 2 ? i2 : i3));
    u16* out       = s == 0 ? o0 : (s == 1 ? o1 : (s == 2 ? o2 : o3));
    const int i = (blockIdx.x * 256 + threadIdx.x) * 4;
    if (i < n) {
        float4 v = *(const float4*)(in + i);
        ushort4 o = { f2b(v.x), f2b(v.y), f2b(v.z), f2b(v.w) };
        *(ushort4*)(out + i) = o;
    }
}

__device__ __forceinline__ void store_c(u16* p, float v)   { *p = f2b(v); }
__device__ __forceinline__ void store_c(float* p, float v) { *p = v; }

// ---------------------------------------------------------------------------
// m97-style GEMM: C[M,N] = A[M,K] @ W[N,K]^T + bias, A/W bf16, fp32 acc.
// 128x128 tile, BK=32, 256 thr = 4 waves, wave owns a 64x64 quadrant (4x4
// MFMA accs). A/B tiles staged via global_load_lds width=16; fragments via
// ds_read_b128. grid.y selects (W,bias,out) for the fused QKV launch.
// ---------------------------------------------------------------------------
template <typename OT>
__global__ __launch_bounds__(256) void gemm128(
    const u16* __restrict__ A,
    const u16* __restrict__ W0, const u16* __restrict__ W1, const u16* __restrict__ W2,
    const float* __restrict__ B0, const float* __restrict__ B1, const float* __restrict__ B2,
    OT* __restrict__ O0, OT* __restrict__ O1, OT* __restrict__ O2,
    int M, int N, int K)
{
    const int sel = blockIdx.y;
    const u16* W      = sel == 0 ? W0 : (sel == 1 ? W1 : W2);
    const float* bias = sel == 0 ? B0 : (sel == 1 ? B1 : B2);
    OT* O             = sel == 0 ? O0 : (sel == 1 ? O1 : O2);

    __shared__ __attribute__((aligned(16))) u16 As[128 * 32];
    __shared__ __attribute__((aligned(16))) u16 Bs[128 * 32];

    const int tid  = threadIdx.x;
    const int lane = tid & 63;
    const int w    = tid >> 6;
    const int l15  = lane & 15;
    const int quad = lane >> 4;

    const int tn = (blockIdx.x & 7) << 7;      // N/128 = 8 tiles
    const int tm = (blockIdx.x >> 3) << 7;

    const int wm = (w >> 1) << 6;              // wave quadrant
    const int wn = (w & 1) << 6;

    f32x4 acc[4][4];
#pragma unroll
    for (int i = 0; i < 4; ++i)
#pragma unroll
        for (int j = 0; j < 4; ++j) acc[i][j] = f32x4{0.f, 0.f, 0.f, 0.f};

    // staging addresses: wave w stages rows [32w, 32w+32) of A and B tiles.
    const int lr = lane >> 2;                  // 0..15
    const int lc = (lane & 3) << 3;            // bf16 col: 0,8,16,24
    const u16* Ag0 = A + (size_t)(tm + 32 * w + lr) * K + lc;
    const u16* Ag1 = Ag0 + (size_t)16 * K;
    const u16* Wg0 = W + (size_t)(tn + 32 * w + lr) * K + lc;
    const u16* Wg1 = Wg0 + (size_t)16 * K;
    u16* Al0 = &As[(32 * w + lr) * 32 + lc];
    u16* Al1 = &As[(32 * w + 16 + lr) * 32 + lc];
    u16* Bl0 = &Bs[(32 * w + lr) * 32 + lc];
    u16* Bl1 = &Bs[(32 * w + 16 + lr) * 32 + lc];

    for (int k0 = 0; k0 < K; k0 += 32) {
        __syncthreads();                       // prior ds_reads complete
        async16(Ag0 + k0, Al0);
        async16(Ag1 + k0, Al1);
        async16(Wg0 + k0, Bl0);
        async16(Wg1 + k0, Bl1);
        asm volatile("s_waitcnt vmcnt(0)" ::: "memory");
        __syncthreads();                       // LDS tiles visible

        bf16x8 a[4], b[4];
#pragma unroll
        for (int i = 0; i < 4; ++i)
            a[i] = *(const bf16x8*)&As[(wm + 16 * i + l15) * 32 + quad * 8];
#pragma unroll
        for (int j = 0; j < 4; ++j)
            b[j] = *(const bf16x8*)&Bs[(wn + 16 * j + l15) * 32 + quad * 8];
#pragma unroll
        for (int i = 0; i < 4; ++i)
#pragma unroll
            for (int j = 0; j < 4; ++j)
                acc[i][j] = mfma16(a[i], b[j], acc[i][j]);
    }

#pragma unroll
    for (int j = 0; j < 4; ++j) {
        const int col = tn + wn + 16 * j + l15;
        const float bj = bias[col];
#pragma unroll
        for (int i = 0; i < 4; ++i) {
            const int row = tm + wm + 16 * i + quad * 4;
#pragma unroll
            for (int r = 0; r < 4; ++r)
                store_c(&O[(size_t)(row + r) * N + col], acc[i][j][r] + bj);
        }
    }
}

// ---------------------------------------------------------------------------
// Flash attention, causal (unchanged from the passing round-4 version).
// Q/K/V/ctx are (B*S, 1024) bf16; head h uses cols [64h,64h+64). One block =
// 4 waves = one 64-row q-tile of one (b,h). ctx aliases Q (disjoint slices).
// ---------------------------------------------------------------------------
__global__ __launch_bounds__(256) void attn_kernel(
    const u16* __restrict__ Q, const u16* __restrict__ K,
    const u16* __restrict__ V, u16* __restrict__ ctx)
{
    __shared__ __attribute__((aligned(16))) u16 Vt[64][72];
    __shared__ __attribute__((aligned(16))) u16 Pl[64][72];

    const int qt = blockIdx.x;
    const int h  = blockIdx.y;
    const int b  = blockIdx.z;
    const int lane = threadIdx.x & 63;
    const int wid  = threadIdx.x >> 6;
    const int l15  = lane & 15;
    const int quad = lane >> 4;
    const int q0 = qt * 64;
    const size_t rowbase = (size_t)b * 2048;
    const int cbase = h * 64;

    const u16* qrow = Q + (rowbase + q0 + wid * 16 + l15) * 1024 + cbase + quad * 8;
    const bf16x8 qa0 = *(const bf16x8*)qrow;
    const bf16x8 qa1 = *(const bf16x8*)(qrow + 32);

    f32x4 o[4];
#pragma unroll
    for (int i = 0; i < 4; ++i) o[i] = f32x4{0.f, 0.f, 0.f, 0.f};
    float m_r[4], l_r[4];
#pragma unroll
    for (int i = 0; i < 4; ++i) { m_r[i] = -1e30f; l_r[i] = 0.f; }

    for (int kt = 0; kt <= qt; ++kt) {
        const int k0 = kt * 64;
        __syncthreads();

        for (int idx = threadIdx.x; idx < 64 * 8; idx += 256) {
            const int r  = idx >> 3;
            const int c8 = (idx & 7) * 8;
            bf16x8 vv = *(const bf16x8*)(V + (rowbase + k0 + r) * 1024 + cbase + c8);
            const u16* vp = (const u16*)&vv;
#pragma unroll
            for (int e = 0; e < 8; ++e) Vt[c8 + e][r] = vp[e];
        }

        f32x4 s[4];
#pragma unroll
        for (int nt = 0; nt < 4; ++nt) {
            const u16* krow = K + (rowbase + k0 + nt * 16 + l15) * 1024 + cbase + quad * 8;
            bf16x8 kb0 = *(const bf16x8*)krow;
            bf16x8 kb1 = *(const bf16x8*)(krow + 32);
            f32x4 z = {0.f, 0.f, 0.f, 0.f};
            z = mfma16(qa0, kb0, z);
            z = mfma16(qa1, kb1, z);
            s[nt] = z;
        }

        float sc[4][4];
#pragma unroll
        for (int nt = 0; nt < 4; ++nt)
#pragma unroll
            for (int r = 0; r < 4; ++r) sc[nt][r] = s[nt][r] * 0.125f;

        if (kt == qt) {
#pragma unroll
            for (int nt = 0; nt < 4; ++nt) {
                const int col = nt * 16 + l15;
#pragma unroll
                for (int r = 0; r < 4; ++r) {
                    const int rowIn = wid * 16 + quad * 4 + r;
                    if (col > rowIn) sc[nt][r] = -1e30f;
                }
            }
        }

        float alpha[4], p[4][4];
#pragma unroll
        for (int r = 0; r < 4; ++r) {
            float rm = fmaxf(fmaxf(sc[0][r], sc[1][r]), fmaxf(sc[2][r], sc[3][r]));
            rm = fmaxf(rm, __shfl_xor(rm, 1));
            rm = fmaxf(rm, __shfl_xor(rm, 2));
            rm = fmaxf(rm, __shfl_xor(rm, 4));
            rm = fmaxf(rm, __shfl_xor(rm, 8));
            const float mn = fmaxf(m_r[r], rm);
            alpha[r] = __expf(m_r[r] - mn);
            m_r[r] = mn;
            float rs = 0.f;
#pragma unroll
            for (int nt = 0; nt < 4; ++nt) {
                p[nt][r] = __expf(sc[nt][r] - mn);
                rs += p[nt][r];
            }
            rs += __shfl_xor(rs, 1);
            rs += __shfl_xor(rs, 2);
            rs += __shfl_xor(rs, 4);
            rs += __shfl_xor(rs, 8);
            l_r[r] = l_r[r] * alpha[r] + rs;
        }

#pragma unroll
        for (int nt = 0; nt < 4; ++nt)
#pragma unroll
            for (int r = 0; r < 4; ++r)
                Pl[wid * 16 + quad * 4 + r][nt * 16 + l15] = f2b(p[nt][r]);
#pragma unroll
        for (int nt = 0; nt < 4; ++nt)
#pragma unroll
            for (int r = 0; r < 4; ++r) o[nt][r] *= alpha[r];

        __syncthreads();

        const u16* prow = &Pl[wid * 16 + l15][quad * 8];
        bf16x8 pa0 = *(const bf16x8*)prow;
        bf16x8 pa1 = *(const bf16x8*)(prow + 32);
#pragma unroll
        for (int nt = 0; nt < 4; ++nt) {
            const u16* vrow = &Vt[nt * 16 + l15][quad * 8];
            bf16x8 vb0 = *(const bf16x8*)vrow;
            bf16x8 vb1 = *(const bf16x8*)(vrow + 32);
            o[nt] = mfma16(pa0, vb0, o[nt]);
            o[nt] = mfma16(pa1, vb1, o[nt]);
        }
    }

#pragma unroll
    for (int nt = 0; nt < 4; ++nt)
#pragma unroll
        for (int r = 0; r < 4; ++r) {
            const float val = o[nt][r] / l_r[r];
            ctx[(rowbase + q0 + wid * 16 + quad * 4 + r) * 1024 + cbase + nt * 16 + l15] =
                f2b(val);
        }
}

extern "C" void kernel_launch(void* const* d_in, const int* in_sizes, int n_in,
                              void* d_out, int out_size, void* d_ws, size_t ws_size,
                              hipStream_t stream) {
    const float* x  = (const float*)d_in[0];
    const float* Wq = (const float*)d_in[1];
    const float* bq = (const float*)d_in[2];
    const float* Wk = (const float*)d_in[3];
    const float* bk = (const float*)d_in[4];
    const float* Wv = (const float*)d_in[5];
    const float* bv = (const float*)d_in[6];
    const float* Wo = (const float*)d_in[7];
    const float* bo = (const float*)d_in[8];
    float* out = (float*)d_out;

    const int N = 1024, K = 1024;
    const int M = in_sizes[0] / K;           // 4096
    const size_t MN = (size_t)M * N;         // 4M
    const size_t WN = (size_t)N * K;         // 1M

    // ws (bf16 units): xb 8MB | 4 weights 8MB | q,kb,v 24MB = 40MB (proven ok)
    u16* xb  = (u16*)d_ws;
    u16* wqb = xb  + MN;
    u16* wkb = wqb + WN;
    u16* wvb = wkb + WN;
    u16* wob = wvb + WN;
    u16* q   = wob + WN;
    u16* kb  = q   + MN;
    u16* v   = kb  + MN;
    u16* ctx = q;                            // alias: disjoint per-block slices

    cast1<<<dim3((int)(MN / 4 / 256)), 256, 0, stream>>>(x, xb, (int)MN);
    cast4<<<dim3((int)(WN / 4 / 256), 4), 256, 0, stream>>>(
        Wq, Wk, Wv, Wo, wqb, wkb, wvb, wob, (int)WN);

    const int gemmBlocks = (M / 128) * (N / 128);     // 256

    gemm128<u16><<<dim3(gemmBlocks, 3), 256, 0, stream>>>(
        xb, wqb, wkb, wvb, bq, bk, bv, q, kb, v, M, N, K);

    attn_kernel<<<dim3(32, 16, 2), 256, 0, stream>>>(q, kb, v, ctx);

    gemm128<float><<<dim3(gemmBlocks, 1), 256, 0, stream>>>(
        ctx, wob, wob, wob, bo, bo, bo, out, out, out, M, N, K);
}

// Round 6
// 289.837 us; speedup vs baseline: 2.5086x; 1.1062x over previous
//
#include <hip/hip_runtime.h>
#include <stdint.h>

typedef unsigned short u16;
typedef __bf16 bf16x8 __attribute__((ext_vector_type(8)));
typedef float f32x4 __attribute__((ext_vector_type(4)));

typedef __attribute__((address_space(3))) uint32_t lds_u32;
typedef __attribute__((address_space(1))) uint32_t glb_u32;

__device__ __forceinline__ f32x4 mfma16(bf16x8 a, bf16x8 b, f32x4 c) {
    return __builtin_amdgcn_mfma_f32_16x16x32_bf16(a, b, c, 0, 0, 0);
}

__device__ __forceinline__ u16 f2b(float f) {
    union { float f; unsigned u32; } v; v.f = f;
    unsigned b = v.u32;
    unsigned r = b + 0x7FFFu + ((b >> 16) & 1u);   // RNE
    return (u16)(r >> 16);
}

__device__ __forceinline__ ushort4 pk4(float a, float b, float c, float d) {
    ushort4 u; u.x = f2b(a); u.y = f2b(b); u.z = f2b(c); u.w = f2b(d); return u;
}

// async global->LDS, 16B per lane (LDS dest = wave base + lane*16)
__device__ __forceinline__ void async16(const u16* g, u16* l) {
    __builtin_amdgcn_global_load_lds((glb_u32*)(uintptr_t)(const void*)g,
                                     (lds_u32*)l, 16, 0, 0);
}

// ---------------------------------------------------------------------------
// fp32 -> bf16 casts
// ---------------------------------------------------------------------------
__global__ __launch_bounds__(256) void cast1(const float* __restrict__ in,
                                             u16* __restrict__ out, int n) {
    const int i = (blockIdx.x * 256 + threadIdx.x) * 4;
    if (i < n) {
        float4 v = *(const float4*)(in + i);
        ushort4 o = { f2b(v.x), f2b(v.y), f2b(v.z), f2b(v.w) };
        *(ushort4*)(out + i) = o;
    }
}

__global__ __launch_bounds__(256) void cast4(
    const float* __restrict__ i0, const float* __restrict__ i1,
    const float* __restrict__ i2, const float* __restrict__ i3,
    u16* __restrict__ o0, u16* __restrict__ o1,
    u16* __restrict__ o2, u16* __restrict__ o3, int n) {
    const int s = blockIdx.y;
    const float* in = s == 0 ? i0 : (s == 1 ? i1 : (s == 2 ? i2 : i3));
    u16* out       = s == 0 ? o0 : (s == 1 ? o1 : (s == 2 ? o2 : o3));
    const int i = (blockIdx.x * 256 + threadIdx.x) * 4;
    if (i < n) {
        float4 v = *(const float4*)(in + i);
        ushort4 o = { f2b(v.x), f2b(v.y), f2b(v.z), f2b(v.w) };
        *(ushort4*)(out + i) = o;
    }
}

__device__ __forceinline__ void store_c(u16* p, float v)   { *p = f2b(v); }
__device__ __forceinline__ void store_c(float* p, float v) { *p = v; }

// ---------------------------------------------------------------------------
// m97-style GEMM: C[M,N] = A[M,K] @ W[N,K]^T + bias, bf16 in, fp32 acc.
// 128x128 tile, BK=32. When VT != null and sel==2 the output is stored
// TRANSPOSED per (b,h): VT[((b*1024 + col) * 2048) + s]  (col = h*64+d).
// ---------------------------------------------------------------------------
template <typename OT>
__global__ __launch_bounds__(256) void gemm128(
    const u16* __restrict__ A,
    const u16* __restrict__ W0, const u16* __restrict__ W1, const u16* __restrict__ W2,
    const float* __restrict__ B0, const float* __restrict__ B1, const float* __restrict__ B2,
    OT* __restrict__ O0, OT* __restrict__ O1, OT* __restrict__ O2,
    u16* __restrict__ VT,
    int M, int N, int K)
{
    const int sel = blockIdx.y;
    const u16* W      = sel == 0 ? W0 : (sel == 1 ? W1 : W2);
    const float* bias = sel == 0 ? B0 : (sel == 1 ? B1 : B2);
    OT* O             = sel == 0 ? O0 : (sel == 1 ? O1 : O2);

    __shared__ __attribute__((aligned(16))) u16 As[128 * 32];
    __shared__ __attribute__((aligned(16))) u16 Bs[128 * 32];

    const int tid  = threadIdx.x;
    const int lane = tid & 63;
    const int w    = tid >> 6;
    const int l15  = lane & 15;
    const int quad = lane >> 4;

    const int tn = (blockIdx.x & 7) << 7;
    const int tm = (blockIdx.x >> 3) << 7;
    const int wm = (w >> 1) << 6;
    const int wn = (w & 1) << 6;

    f32x4 acc[4][4];
#pragma unroll
    for (int i = 0; i < 4; ++i)
#pragma unroll
        for (int j = 0; j < 4; ++j) acc[i][j] = f32x4{0.f, 0.f, 0.f, 0.f};

    const int lr = lane >> 2;
    const int lc = (lane & 3) << 3;
    const u16* Ag0 = A + (size_t)(tm + 32 * w + lr) * K + lc;
    const u16* Ag1 = Ag0 + (size_t)16 * K;
    const u16* Wg0 = W + (size_t)(tn + 32 * w + lr) * K + lc;
    const u16* Wg1 = Wg0 + (size_t)16 * K;
    u16* Al0 = &As[(32 * w + lr) * 32 + lc];
    u16* Al1 = &As[(32 * w + 16 + lr) * 32 + lc];
    u16* Bl0 = &Bs[(32 * w + lr) * 32 + lc];
    u16* Bl1 = &Bs[(32 * w + 16 + lr) * 32 + lc];

    for (int k0 = 0; k0 < K; k0 += 32) {
        __syncthreads();
        async16(Ag0 + k0, Al0);
        async16(Ag1 + k0, Al1);
        async16(Wg0 + k0, Bl0);
        async16(Wg1 + k0, Bl1);
        asm volatile("s_waitcnt vmcnt(0)" ::: "memory");
        __syncthreads();

        bf16x8 a[4], b[4];
#pragma unroll
        for (int i = 0; i < 4; ++i)
            a[i] = *(const bf16x8*)&As[(wm + 16 * i + l15) * 32 + quad * 8];
#pragma unroll
        for (int j = 0; j < 4; ++j)
            b[j] = *(const bf16x8*)&Bs[(wn + 16 * j + l15) * 32 + quad * 8];
#pragma unroll
        for (int i = 0; i < 4; ++i)
#pragma unroll
            for (int j = 0; j < 4; ++j)
                acc[i][j] = mfma16(a[i], b[j], acc[i][j]);
    }

    if (VT != nullptr && sel == 2) {
        // transposed store: VT row = b*1024 + col, inner dim = s (0..2047)
#pragma unroll
        for (int j = 0; j < 4; ++j) {
            const int col = tn + wn + 16 * j + l15;
            const float bj = bias[col];
#pragma unroll
            for (int i = 0; i < 4; ++i) {
                const int row = tm + wm + 16 * i + quad * 4;
                const int bb = row >> 11, s = row & 2047;
                *(ushort4*)&VT[((size_t)(bb << 10) + col) * 2048 + s] =
                    pk4(acc[i][j][0] + bj, acc[i][j][1] + bj,
                        acc[i][j][2] + bj, acc[i][j][3] + bj);
            }
        }
    } else {
#pragma unroll
        for (int j = 0; j < 4; ++j) {
            const int col = tn + wn + 16 * j + l15;
            const float bj = bias[col];
#pragma unroll
            for (int i = 0; i < 4; ++i) {
                const int row = tm + wm + 16 * i + quad * 4;
#pragma unroll
                for (int r = 0; r < 4; ++r)
                    store_c(&O[(size_t)(row + r) * N + col], acc[i][j][r] + bj);
            }
        }
    }
}

// ---------------------------------------------------------------------------
// Barrier-free flash attention (S^T trick), causal.
// Q/K/ctx: (B*S, 1024) bf16 row-major. VT: [b*1024 + h*64 + d][s] bf16.
// One wave = 2 adjacent 16-row q-strips (rows 32m..32m+31) of one (b,h);
// identical k-tile ranges -> shared K/V loads. No __syncthreads anywhere:
// the P round-trip LDS is wave-private.
// S^T = K·Q^T  (A=K rows, B=Q rows; D: row=key=quad*4+r, col=q=l15)
// O^T = V^T·P^T (A=VT rows,  B=P rows from LDS; D: row=d, col=q)
// ---------------------------------------------------------------------------
__global__ __launch_bounds__(256) void attn2(
    const u16* __restrict__ Q, const u16* __restrict__ Kb,
    const u16* __restrict__ VT, u16* __restrict__ ctx)
{
    __shared__ __attribute__((aligned(16))) u16 Pt[4][32][72];

    const int lane = threadIdx.x & 63;
    const int wid  = threadIdx.x >> 6;
    const int l15  = lane & 15;
    const int quad = lane >> 4;
    const int h = blockIdx.y, b = blockIdx.z;
    const int m = 63 - (blockIdx.x * 4 + wid);   // heavy pairs first
    const int q0 = m * 32;
    const size_t rowbase = (size_t)b * 2048;
    const int cbase = h * 64;
    const size_t vtrow = (size_t)b * 1024 + cbase;

    const u16* qpA = Q + (rowbase + q0 + l15) * 1024 + cbase + quad * 8;
    const u16* qpB = qpA + (size_t)16 * 1024;
    const bf16x8 qA0 = *(const bf16x8*)qpA, qA1 = *(const bf16x8*)(qpA + 32);
    const bf16x8 qB0 = *(const bf16x8*)qpB, qB1 = *(const bf16x8*)(qpB + 32);

    f32x4 oA[4], oB[4];
#pragma unroll
    for (int i = 0; i < 4; ++i) { oA[i] = f32x4{0,0,0,0}; oB[i] = f32x4{0,0,0,0}; }
    float mA = -1e30f, lA = 0.f, mB = -1e30f, lB = 0.f;
    const int qgA = q0 + l15, qgB = q0 + 16 + l15;
    const int nkt = (m >> 1) + 1;
    const float SC = 0.18033688011112042f;       // 0.125 * log2(e)

    u16 (*ptw)[72] = Pt[wid];

    for (int kt = 0; kt < nkt; ++kt) {
        const int k0 = kt * 64;
        const bool last = (kt == nkt - 1);

        // issue all K and V fragment loads up front (independent)
        bf16x8 kf[4][2], vf[4][2];
#pragma unroll
        for (int t = 0; t < 4; ++t) {
            const u16* kp = Kb + (rowbase + k0 + t * 16 + l15) * 1024 + cbase + quad * 8;
            kf[t][0] = *(const bf16x8*)kp;
            kf[t][1] = *(const bf16x8*)(kp + 32);
        }
#pragma unroll
        for (int nt = 0; nt < 4; ++nt) {
            const u16* vp = VT + (vtrow + nt * 16 + l15) * 2048 + k0 + quad * 8;
            vf[nt][0] = *(const bf16x8*)vp;
            vf[nt][1] = *(const bf16x8*)(vp + 32);
        }

        // S^T tiles
        float pA[4][4], pB[4][4];
#pragma unroll
        for (int t = 0; t < 4; ++t) {
            f32x4 zA = {0,0,0,0}, zB = {0,0,0,0};
            zA = mfma16(kf[t][0], qA0, zA); zA = mfma16(kf[t][1], qA1, zA);
            zB = mfma16(kf[t][0], qB0, zB); zB = mfma16(kf[t][1], qB1, zB);
#pragma unroll
            for (int r = 0; r < 4; ++r) {
                float a = zA[r] * SC, bb = zB[r] * SC;
                if (last) {
                    const int key = k0 + t * 16 + quad * 4 + r;
                    if (key > qgA) a  = -1e30f;
                    if (key > qgB) bb = -1e30f;
                }
                pA[t][r] = a; pB[t][r] = bb;
            }
        }

        // online softmax, strip A (stats per q=l15; reduce across quads)
        {
            float rm = -1e30f;
#pragma unroll
            for (int t = 0; t < 4; ++t)
#pragma unroll
                for (int r = 0; r < 4; ++r) rm = fmaxf(rm, pA[t][r]);
            rm = fmaxf(rm, __shfl_xor(rm, 16));
            rm = fmaxf(rm, __shfl_xor(rm, 32));
            const float mn = fmaxf(mA, rm);
            const float al = exp2f(mA - mn);
            mA = mn;
            float rs = 0.f;
#pragma unroll
            for (int t = 0; t < 4; ++t)
#pragma unroll
                for (int r = 0; r < 4; ++r) { pA[t][r] = exp2f(pA[t][r] - mn); rs += pA[t][r]; }
            rs += __shfl_xor(rs, 16);
            rs += __shfl_xor(rs, 32);
            lA = lA * al + rs;
#pragma unroll
            for (int nt = 0; nt < 4; ++nt)
#pragma unroll
                for (int r = 0; r < 4; ++r) oA[nt][r] *= al;
        }
        // strip B
        {
            float rm = -1e30f;
#pragma unroll
            for (int t = 0; t < 4; ++t)
#pragma unroll
                for (int r = 0; r < 4; ++r) rm = fmaxf(rm, pB[t][r]);
            rm = fmaxf(rm, __shfl_xor(rm, 16));
            rm = fmaxf(rm, __shfl_xor(rm, 32));
            const float mn = fmaxf(mB, rm);
            const float al = exp2f(mB - mn);
            mB = mn;
            float rs = 0.f;
#pragma unroll
            for (int t = 0; t < 4; ++t)
#pragma unroll
                for (int r = 0; r < 4; ++r) { pB[t][r] = exp2f(pB[t][r] - mn); rs += pB[t][r]; }
            rs += __shfl_xor(rs, 16);
            rs += __shfl_xor(rs, 32);
            lB = lB * al + rs;
#pragma unroll
            for (int nt = 0; nt < 4; ++nt)
#pragma unroll
                for (int r = 0; r < 4; ++r) oB[nt][r] *= al;
        }

        // P (C-layout) -> LDS rows [q][key] (wave-private, packed 8B writes)
#pragma unroll
        for (int t = 0; t < 4; ++t) {
            *(ushort4*)&ptw[l15][t * 16 + quad * 4] =
                pk4(pA[t][0], pA[t][1], pA[t][2], pA[t][3]);
            *(ushort4*)&ptw[16 + l15][t * 16 + quad * 4] =
                pk4(pB[t][0], pB[t][1], pB[t][2], pB[t][3]);
        }

        // B-fragments for PV (k = key contiguous)
        const bf16x8 bAlo = *(const bf16x8*)&ptw[l15][quad * 8];
        const bf16x8 bAhi = *(const bf16x8*)&ptw[l15][32 + quad * 8];
        const bf16x8 bBlo = *(const bf16x8*)&ptw[16 + l15][quad * 8];
        const bf16x8 bBhi = *(const bf16x8*)&ptw[16 + l15][32 + quad * 8];

#pragma unroll
        for (int nt = 0; nt < 4; ++nt) {
            oA[nt] = mfma16(vf[nt][0], bAlo, oA[nt]);
            oA[nt] = mfma16(vf[nt][1], bAhi, oA[nt]);
            oB[nt] = mfma16(vf[nt][0], bBlo, oB[nt]);
            oB[nt] = mfma16(vf[nt][1], bBhi, oB[nt]);
        }
    }

    const float iA = 1.0f / lA, iB = 1.0f / lB;
#pragma unroll
    for (int nt = 0; nt < 4; ++nt) {
        *(ushort4*)&ctx[(rowbase + qgA) * 1024 + cbase + nt * 16 + quad * 4] =
            pk4(oA[nt][0] * iA, oA[nt][1] * iA, oA[nt][2] * iA, oA[nt][3] * iA);
        *(ushort4*)&ctx[(rowbase + qgB) * 1024 + cbase + nt * 16 + quad * 4] =
            pk4(oB[nt][0] * iB, oB[nt][1] * iB, oB[nt][2] * iB, oB[nt][3] * iB);
    }
}

extern "C" void kernel_launch(void* const* d_in, const int* in_sizes, int n_in,
                              void* d_out, int out_size, void* d_ws, size_t ws_size,
                              hipStream_t stream) {
    const float* x  = (const float*)d_in[0];
    const float* Wq = (const float*)d_in[1];
    const float* bq = (const float*)d_in[2];
    const float* Wk = (const float*)d_in[3];
    const float* bk = (const float*)d_in[4];
    const float* Wv = (const float*)d_in[5];
    const float* bv = (const float*)d_in[6];
    const float* Wo = (const float*)d_in[7];
    const float* bo = (const float*)d_in[8];
    float* out = (float*)d_out;

    const int N = 1024, K = 1024;
    const int M = in_sizes[0] / K;           // 4096
    const size_t MN = (size_t)M * N;
    const size_t WN = (size_t)N * K;

    // ws (bf16 units): xb | wq wk wv wo | q | kb | vt  = 40MB (proven ok)
    u16* xb  = (u16*)d_ws;
    u16* wqb = xb  + MN;
    u16* wkb = wqb + WN;
    u16* wvb = wkb + WN;
    u16* wob = wvb + WN;
    u16* q   = wob + WN;
    u16* kb  = q   + MN;
    u16* vt  = kb  + MN;                     // V^T: [b*1024 + h*64 + d][s]
    u16* ctx = q;                            // alias: disjoint per-wave slices

    cast1<<<dim3((int)(MN / 4 / 256)), 256, 0, stream>>>(x, xb, (int)MN);
    cast4<<<dim3((int)(WN / 4 / 256), 4), 256, 0, stream>>>(
        Wq, Wk, Wv, Wo, wqb, wkb, wvb, wob, (int)WN);

    const int gemmBlocks = (M / 128) * (N / 128);     // 256

    // QKV: sel 0 -> q (row-major), sel 1 -> kb (row-major), sel 2 -> vt (transposed)
    gemm128<u16><<<dim3(gemmBlocks, 3), 256, 0, stream>>>(
        xb, wqb, wkb, wvb, bq, bk, bv, q, kb, /*unused*/ q, vt, M, N, K);

    // barrier-free attention: 64 strip-pairs / 4 per block = 16 blocks x H x B
    attn2<<<dim3(16, 16, 2), 256, 0, stream>>>(q, kb, vt, ctx);

    gemm128<float><<<dim3(gemmBlocks, 1), 256, 0, stream>>>(
        ctx, wob, wob, wob, bo, bo, bo, out, out, out, nullptr, M, N, K);
}

// Round 7
// 274.598 us; speedup vs baseline: 2.6478x; 1.0555x over previous
//
#include <hip/hip_runtime.h>
#include <stdint.h>

typedef unsigned short u16;
typedef __bf16 bf16x8 __attribute__((ext_vector_type(8)));
typedef float f32x4 __attribute__((ext_vector_type(4)));

typedef __attribute__((address_space(3))) uint32_t lds_u32;
typedef __attribute__((address_space(1))) uint32_t glb_u32;

__device__ __forceinline__ f32x4 mfma16(bf16x8 a, bf16x8 b, f32x4 c) {
    return __builtin_amdgcn_mfma_f32_16x16x32_bf16(a, b, c, 0, 0, 0);
}

__device__ __forceinline__ u16 f2b(float f) {
    union { float f; unsigned u32; } v; v.f = f;
    unsigned b = v.u32;
    unsigned r = b + 0x7FFFu + ((b >> 16) & 1u);   // RNE
    return (u16)(r >> 16);
}

__device__ __forceinline__ ushort4 pk4(float a, float b, float c, float d) {
    ushort4 u; u.x = f2b(a); u.y = f2b(b); u.z = f2b(c); u.w = f2b(d); return u;
}

// async global->LDS, 16B per lane (LDS dest = wave base + lane*16)
__device__ __forceinline__ void async16(const u16* g, u16* l) {
    __builtin_amdgcn_global_load_lds((glb_u32*)(uintptr_t)(const void*)g,
                                     (lds_u32*)l, 16, 0, 0);
}

// ---------------------------------------------------------------------------
// fp32 -> bf16 casts
// ---------------------------------------------------------------------------
__global__ __launch_bounds__(256) void cast1(const float* __restrict__ in,
                                             u16* __restrict__ out, int n) {
    const int i = (blockIdx.x * 256 + threadIdx.x) * 4;
    if (i < n) {
        float4 v = *(const float4*)(in + i);
        ushort4 o = { f2b(v.x), f2b(v.y), f2b(v.z), f2b(v.w) };
        *(ushort4*)(out + i) = o;
    }
}

__global__ __launch_bounds__(256) void cast4(
    const float* __restrict__ i0, const float* __restrict__ i1,
    const float* __restrict__ i2, const float* __restrict__ i3,
    u16* __restrict__ o0, u16* __restrict__ o1,
    u16* __restrict__ o2, u16* __restrict__ o3, int n) {
    const int s = blockIdx.y;
    const float* in = s == 0 ? i0 : (s == 1 ? i1 : (s == 2 ? i2 : i3));
    u16* out       = s == 0 ? o0 : (s == 1 ? o1 : (s == 2 ? o2 : o3));
    const int i = (blockIdx.x * 256 + threadIdx.x) * 4;
    if (i < n) {
        float4 v = *(const float4*)(in + i);
        ushort4 o = { f2b(v.x), f2b(v.y), f2b(v.z), f2b(v.w) };
        *(ushort4*)(out + i) = o;
    }
}

__device__ __forceinline__ void store_c(u16* p, float v)   { *p = f2b(v); }
__device__ __forceinline__ void store_c(float* p, float v) { *p = v; }

// ---------------------------------------------------------------------------
// m97-style GEMM (unchanged from round 6, which passed).
// ---------------------------------------------------------------------------
template <typename OT>
__global__ __launch_bounds__(256) void gemm128(
    const u16* __restrict__ A,
    const u16* __restrict__ W0, const u16* __restrict__ W1, const u16* __restrict__ W2,
    const float* __restrict__ B0, const float* __restrict__ B1, const float* __restrict__ B2,
    OT* __restrict__ O0, OT* __restrict__ O1, OT* __restrict__ O2,
    u16* __restrict__ VT,
    int M, int N, int K)
{
    const int sel = blockIdx.y;
    const u16* W      = sel == 0 ? W0 : (sel == 1 ? W1 : W2);
    const float* bias = sel == 0 ? B0 : (sel == 1 ? B1 : B2);
    OT* O             = sel == 0 ? O0 : (sel == 1 ? O1 : O2);

    __shared__ __attribute__((aligned(16))) u16 As[128 * 32];
    __shared__ __attribute__((aligned(16))) u16 Bs[128 * 32];

    const int tid  = threadIdx.x;
    const int lane = tid & 63;
    const int w    = tid >> 6;
    const int l15  = lane & 15;
    const int quad = lane >> 4;

    const int tn = (blockIdx.x & 7) << 7;
    const int tm = (blockIdx.x >> 3) << 7;
    const int wm = (w >> 1) << 6;
    const int wn = (w & 1) << 6;

    f32x4 acc[4][4];
#pragma unroll
    for (int i = 0; i < 4; ++i)
#pragma unroll
        for (int j = 0; j < 4; ++j) acc[i][j] = f32x4{0.f, 0.f, 0.f, 0.f};

    const int lr = lane >> 2;
    const int lc = (lane & 3) << 3;
    const u16* Ag0 = A + (size_t)(tm + 32 * w + lr) * K + lc;
    const u16* Ag1 = Ag0 + (size_t)16 * K;
    const u16* Wg0 = W + (size_t)(tn + 32 * w + lr) * K + lc;
    const u16* Wg1 = Wg0 + (size_t)16 * K;
    u16* Al0 = &As[(32 * w + lr) * 32 + lc];
    u16* Al1 = &As[(32 * w + 16 + lr) * 32 + lc];
    u16* Bl0 = &Bs[(32 * w + lr) * 32 + lc];
    u16* Bl1 = &Bs[(32 * w + 16 + lr) * 32 + lc];

    for (int k0 = 0; k0 < K; k0 += 32) {
        __syncthreads();
        async16(Ag0 + k0, Al0);
        async16(Ag1 + k0, Al1);
        async16(Wg0 + k0, Bl0);
        async16(Wg1 + k0, Bl1);
        asm volatile("s_waitcnt vmcnt(0)" ::: "memory");
        __syncthreads();

        bf16x8 a[4], b[4];
#pragma unroll
        for (int i = 0; i < 4; ++i)
            a[i] = *(const bf16x8*)&As[(wm + 16 * i + l15) * 32 + quad * 8];
#pragma unroll
        for (int j = 0; j < 4; ++j)
            b[j] = *(const bf16x8*)&Bs[(wn + 16 * j + l15) * 32 + quad * 8];
#pragma unroll
        for (int i = 0; i < 4; ++i)
#pragma unroll
            for (int j = 0; j < 4; ++j)
                acc[i][j] = mfma16(a[i], b[j], acc[i][j]);
    }

    if (VT != nullptr && sel == 2) {
#pragma unroll
        for (int j = 0; j < 4; ++j) {
            const int col = tn + wn + 16 * j + l15;
            const float bj = bias[col];
#pragma unroll
            for (int i = 0; i < 4; ++i) {
                const int row = tm + wm + 16 * i + quad * 4;
                const int bb = row >> 11, s = row & 2047;
                *(ushort4*)&VT[((size_t)(bb << 10) + col) * 2048 + s] =
                    pk4(acc[i][j][0] + bj, acc[i][j][1] + bj,
                        acc[i][j][2] + bj, acc[i][j][3] + bj);
            }
        }
    } else {
#pragma unroll
        for (int j = 0; j < 4; ++j) {
            const int col = tn + wn + 16 * j + l15;
            const float bj = bias[col];
#pragma unroll
            for (int i = 0; i < 4; ++i) {
                const int row = tm + wm + 16 * i + quad * 4;
#pragma unroll
                for (int r = 0; r < 4; ++r)
                    store_c(&O[(size_t)(row + r) * N + col], acc[i][j][r] + bj);
            }
        }
    }
}

// ---------------------------------------------------------------------------
// attn3: barrier-free causal flash attention, uniform waves + K prefetch.
// One wave owns strips sL=j (16 rows) and sH=127-j of one (b,h); they share
// the k-loop (light's tile range is a subset of heavy's). Work per wave =
// KL+KH+2 = 33 strip-tiles, identical for all waves. K-tile fragments are
// register double-buffered (prefetch kt+1 before computing kt); V loads
// issue at iteration top and are consumed only after softmax.
// S^T = K·Q^T (D: row=key, col=q);  O^T = V^T·P^T (D: row=d, col=q).
// ---------------------------------------------------------------------------
__device__ __forceinline__ void load_ktile(const u16* __restrict__ base, int kt,
                                           int l15, int quad, bf16x8 kf[4][2]) {
#pragma unroll
    for (int t = 0; t < 4; ++t) {
        const u16* kp = base + (size_t)(kt * 64 + t * 16 + l15) * 1024 + quad * 8;
        kf[t][0] = *(const bf16x8*)kp;
        kf[t][1] = *(const bf16x8*)(kp + 32);
    }
}
__device__ __forceinline__ void load_vtile(const u16* __restrict__ base, int kt,
                                           int l15, int quad, bf16x8 vf[4][2]) {
#pragma unroll
    for (int t = 0; t < 4; ++t) {
        const u16* vp = base + (size_t)(t * 16 + l15) * 2048 + kt * 64 + quad * 8;
        vf[t][0] = *(const bf16x8*)vp;
        vf[t][1] = *(const bf16x8*)(vp + 32);
    }
}

__global__ __launch_bounds__(256) void attn3(
    const u16* __restrict__ Q, const u16* __restrict__ Kb,
    const u16* __restrict__ VT, u16* __restrict__ ctx)
{
    __shared__ __attribute__((aligned(16))) u16 Pt[4][32][72];

    const int lane = threadIdx.x & 63;
    const int wid  = threadIdx.x >> 6;
    const int l15  = lane & 15;
    const int quad = lane >> 4;
    const int h = blockIdx.y, b = blockIdx.z;
    const int bx = blockIdx.x;
    const int j  = (((wid + bx) & 3) << 4) + bx;   // light strip index, 0..63
    const int sL = j, sH = 127 - j;
    const int KL = sL >> 2, KH = sH >> 2;          // KL <= 15 < 16 <= KH

    const size_t rowbase = (size_t)b * 2048;
    const int cbase = h * 64;
    const u16* kbase = Kb + rowbase * 1024 + cbase;
    const u16* vbase = VT + ((size_t)b * 1024 + cbase) * 2048;

    const int qgL = sL * 16 + l15, qgH = sH * 16 + l15;

    const u16* qpL = Q + (rowbase + qgL) * 1024 + cbase + quad * 8;
    const u16* qpH = Q + (rowbase + qgH) * 1024 + cbase + quad * 8;
    const bf16x8 qL0 = *(const bf16x8*)qpL, qL1 = *(const bf16x8*)(qpL + 32);
    const bf16x8 qH0 = *(const bf16x8*)qpH, qH1 = *(const bf16x8*)(qpH + 32);

    f32x4 oL[4], oH[4];
#pragma unroll
    for (int i = 0; i < 4; ++i) { oL[i] = f32x4{0,0,0,0}; oH[i] = f32x4{0,0,0,0}; }
    float mL = -1e30f, lL = 0.f, mH = -1e30f, lH = 0.f;
    const float SC = 0.18033688011112042f;         // 0.125 * log2(e)

    u16 (*ptw)[72] = Pt[wid];

    bf16x8 kc[4][2], kn[4][2], vf[4][2];
    load_ktile(kbase, 0, l15, quad, kc);

    for (int kt = 0; kt <= KH; ++kt) {
        load_vtile(vbase, kt, l15, quad, vf);      // consumed after softmax
        if (kt < KH) load_ktile(kbase, kt + 1, l15, quad, kn);
        const bool doL = (kt <= KL);
        const bool mskH = (kt == KH), mskL = (kt == KL);

        // S^T tiles
        float pH[4][4], pL[4][4];
#pragma unroll
        for (int t = 0; t < 4; ++t) {
            f32x4 z = {0,0,0,0};
            z = mfma16(kc[t][0], qH0, z);
            z = mfma16(kc[t][1], qH1, z);
#pragma unroll
            for (int r = 0; r < 4; ++r) {
                float v = z[r] * SC;
                if (mskH && (kt * 64 + t * 16 + quad * 4 + r) > qgH) v = -1e30f;
                pH[t][r] = v;
            }
        }
        if (doL) {
#pragma unroll
            for (int t = 0; t < 4; ++t) {
                f32x4 z = {0,0,0,0};
                z = mfma16(kc[t][0], qL0, z);
                z = mfma16(kc[t][1], qL1, z);
#pragma unroll
                for (int r = 0; r < 4; ++r) {
                    float v = z[r] * SC;
                    if (mskL && (kt * 64 + t * 16 + quad * 4 + r) > qgL) v = -1e30f;
                    pL[t][r] = v;
                }
            }
        }

        // online softmax, heavy strip (stats per q=l15, reduce across quads)
        {
            float rm = -1e30f;
#pragma unroll
            for (int t = 0; t < 4; ++t)
#pragma unroll
                for (int r = 0; r < 4; ++r) rm = fmaxf(rm, pH[t][r]);
            rm = fmaxf(rm, __shfl_xor(rm, 16));
            rm = fmaxf(rm, __shfl_xor(rm, 32));
            const float mn = fmaxf(mH, rm);
            const float al = exp2f(mH - mn);
            mH = mn;
            float rs = 0.f;
#pragma unroll
            for (int t = 0; t < 4; ++t)
#pragma unroll
                for (int r = 0; r < 4; ++r) { pH[t][r] = exp2f(pH[t][r] - mn); rs += pH[t][r]; }
            rs += __shfl_xor(rs, 16);
            rs += __shfl_xor(rs, 32);
            lH = lH * al + rs;
#pragma unroll
            for (int t = 0; t < 4; ++t)
#pragma unroll
                for (int r = 0; r < 4; ++r) oH[t][r] *= al;
        }
        if (doL) {
            float rm = -1e30f;
#pragma unroll
            for (int t = 0; t < 4; ++t)
#pragma unroll
                for (int r = 0; r < 4; ++r) rm = fmaxf(rm, pL[t][r]);
            rm = fmaxf(rm, __shfl_xor(rm, 16));
            rm = fmaxf(rm, __shfl_xor(rm, 32));
            const float mn = fmaxf(mL, rm);
            const float al = exp2f(mL - mn);
            mL = mn;
            float rs = 0.f;
#pragma unroll
            for (int t = 0; t < 4; ++t)
#pragma unroll
                for (int r = 0; r < 4; ++r) { pL[t][r] = exp2f(pL[t][r] - mn); rs += pL[t][r]; }
            rs += __shfl_xor(rs, 16);
            rs += __shfl_xor(rs, 32);
            lL = lL * al + rs;
#pragma unroll
            for (int t = 0; t < 4; ++t)
#pragma unroll
                for (int r = 0; r < 4; ++r) oL[t][r] *= al;
        }

        // P (C-layout) -> wave-private LDS rows [q][key]; heavy rows 16..31
#pragma unroll
        for (int t = 0; t < 4; ++t)
            *(ushort4*)&ptw[16 + l15][t * 16 + quad * 4] =
                pk4(pH[t][0], pH[t][1], pH[t][2], pH[t][3]);
        if (doL) {
#pragma unroll
            for (int t = 0; t < 4; ++t)
                *(ushort4*)&ptw[l15][t * 16 + quad * 4] =
                    pk4(pL[t][0], pL[t][1], pL[t][2], pL[t][3]);
        }

        const bf16x8 bH0 = *(const bf16x8*)&ptw[16 + l15][quad * 8];
        const bf16x8 bH1 = *(const bf16x8*)&ptw[16 + l15][32 + quad * 8];
#pragma unroll
        for (int t = 0; t < 4; ++t) {
            oH[t] = mfma16(vf[t][0], bH0, oH[t]);
            oH[t] = mfma16(vf[t][1], bH1, oH[t]);
        }
        if (doL) {
            const bf16x8 bL0 = *(const bf16x8*)&ptw[l15][quad * 8];
            const bf16x8 bL1 = *(const bf16x8*)&ptw[l15][32 + quad * 8];
#pragma unroll
            for (int t = 0; t < 4; ++t) {
                oL[t] = mfma16(vf[t][0], bL0, oL[t]);
                oL[t] = mfma16(vf[t][1], bL1, oL[t]);
            }
        }

#pragma unroll
        for (int t = 0; t < 4; ++t) { kc[t][0] = kn[t][0]; kc[t][1] = kn[t][1]; }
    }

    const float iL = 1.0f / lL, iH = 1.0f / lH;
#pragma unroll
    for (int t = 0; t < 4; ++t) {
        *(ushort4*)&ctx[(rowbase + qgL) * 1024 + cbase + t * 16 + quad * 4] =
            pk4(oL[t][0] * iL, oL[t][1] * iL, oL[t][2] * iL, oL[t][3] * iL);
        *(ushort4*)&ctx[(rowbase + qgH) * 1024 + cbase + t * 16 + quad * 4] =
            pk4(oH[t][0] * iH, oH[t][1] * iH, oH[t][2] * iH, oH[t][3] * iH);
    }
}

extern "C" void kernel_launch(void* const* d_in, const int* in_sizes, int n_in,
                              void* d_out, int out_size, void* d_ws, size_t ws_size,
                              hipStream_t stream) {
    const float* x  = (const float*)d_in[0];
    const float* Wq = (const float*)d_in[1];
    const float* bq = (const float*)d_in[2];
    const float* Wk = (const float*)d_in[3];
    const float* bk = (const float*)d_in[4];
    const float* Wv = (const float*)d_in[5];
    const float* bv = (const float*)d_in[6];
    const float* Wo = (const float*)d_in[7];
    const float* bo = (const float*)d_in[8];
    float* out = (float*)d_out;

    const int N = 1024, K = 1024;
    const int M = in_sizes[0] / K;           // 4096
    const size_t MN = (size_t)M * N;
    const size_t WN = (size_t)N * K;

    u16* xb  = (u16*)d_ws;
    u16* wqb = xb  + MN;
    u16* wkb = wqb + WN;
    u16* wvb = wkb + WN;
    u16* wob = wvb + WN;
    u16* q   = wob + WN;
    u16* kb  = q   + MN;
    u16* vt  = kb  + MN;                     // V^T: [b*1024 + h*64 + d][s]
    u16* ctx = q;                            // alias: disjoint per-wave strips

    cast1<<<dim3((int)(MN / 4 / 256)), 256, 0, stream>>>(x, xb, (int)MN);
    cast4<<<dim3((int)(WN / 4 / 256), 4), 256, 0, stream>>>(
        Wq, Wk, Wv, Wo, wqb, wkb, wvb, wob, (int)WN);

    const int gemmBlocks = (M / 128) * (N / 128);     // 256

    gemm128<u16><<<dim3(gemmBlocks, 3), 256, 0, stream>>>(
        xb, wqb, wkb, wvb, bq, bk, bv, q, kb, /*unused*/ q, vt, M, N, K);

    attn3<<<dim3(16, 16, 2), 256, 0, stream>>>(q, kb, vt, ctx);

    gemm128<float><<<dim3(gemmBlocks, 1), 256, 0, stream>>>(
        ctx, wob, wob, wob, bo, bo, bo, out, out, out, nullptr, M, N, K);
}